// Round 2
// baseline (77.279 us; speedup 1.0000x reference)
//
#include <hip/hip_runtime.h>

// Problem constants (fixed by the harness: B=4096, K=128, C=64)
#define K_KP   128
#define C_COMP 64
#define KPB    4              // k's per block (one per wave)

typedef float v2f __attribute__((ext_vector_type(2)));

#if __has_builtin(__builtin_amdgcn_exp2f)
#define EXP2F(x) __builtin_amdgcn_exp2f(x)
#else
#define EXP2F(x) exp2f(x)
#endif
#if __has_builtin(__builtin_amdgcn_logf)
#define LOG2F_(x) __builtin_amdgcn_logf(x)
#else
#define LOG2F_(x) __log2f(x)
#endif
#if __has_builtin(__builtin_amdgcn_rcpf)
#define RCPF(x) __builtin_amdgcn_rcpf(x)
#else
#define RCPF(x) (1.0f/(x))
#endif
#if __has_builtin(__builtin_amdgcn_rsqf)
#define RSQF(x) __builtin_amdgcn_rsqf(x)
#else
#define RSQF(x) rsqrtf(x)
#endif

// broadcast lane l's value of v to all lanes (lands in an SGPR)
__device__ __forceinline__ float rlane(float v, int l) {
    union { float f; int i; } u; u.f = v;
    u.i = __builtin_amdgcn_readlane(u.i, l);
    return u.f;
}

// per-component eval on a v2f pair of b-values; all 6 constants are
// wave-uniform SGPRs (each VALU op reads at most 1 SGPR).
// Relies on -ffp-contract for fma fusion.
#define EVAL(m0, m1, i00, i01, i11, lc)                                 \
    {                                                                   \
        v2f d0 = ZX - (m0);                                             \
        v2f d1 = ZY - (m1);                                             \
        v2f s0 = (i00) * d0 + (i01) * d1;  /* k2 * (Sigma^-1 diff)_0 */ \
        v2f s1 = (i01) * d0 + (i11) * d1;                               \
        v2f arg = (lc) - d0 * s0 - d1 * s1; /* lc - k2*maha */          \
        v2f e;                                                          \
        e.x = EXP2F(arg.x);                                             \
        e.y = EXP2F(arg.y);                                             \
        pdf += e;                                                       \
        G0  += e * s0;                                                  \
        G1  += e * s1;                                                  \
    }

// 256 threads = 4 waves, each wave owns ONE k. Lane c derives component c's
// constants from coalesced global loads; the unrolled c-loop broadcasts them
// via v_readlane (no LDS, no barriers, no workspace).
// Grid = (K/4) * (B/128) = 1024 blocks -> 4 blocks/CU, 16 waves/CU.
__global__ __launch_bounds__(256, 4) void recovery_kernel(
    const float* __restrict__ z,       // [B,K,2]
    const float* __restrict__ weights, // [K,C]
    const float* __restrict__ means,   // [K,C,2]
    const float* __restrict__ covs,    // [K,C,2,2]
    const float* __restrict__ scale,   // [K,2]
    float* __restrict__ out, int B)
{
    const int t    = threadIdx.x;
    const int lane = t & 63;
    const int wv   = __builtin_amdgcn_readfirstlane(t >> 6);  // force SGPR

    // XCD-bijective swizzle (1024 blocks % 8 XCDs == 0): consecutive work
    // (same bb, all kb) lands on one XCD -> shared z lines / out lines stay
    // in one L2.
    const int bid = blockIdx.x;
    const int swz = (bid & 7) * 128 + (bid >> 3);
    const int kb  = swz & 31;                 // 32 k-blocks of 4
    const int bb  = swz >> 5;                 // 32 b-blocks of 128
    const int k   = kb * KPB + wv;            // wave-uniform
    const int b0  = bb * 128;

    // ---- per-lane param derivation: lane c owns component c of this k ----
    const float K2       = 0.72134752044f;    // 0.5 * log2(e)
    const float LOG2_2PI = 2.6514961295f;     // log2(2*pi)
    const int g = k * C_COMP + lane;          // coalesced across the wave
    float  w  = weights[g];
    float2 m  = ((const float2*)means)[g];
    float4 cv = ((const float4*)covs)[g];     // a, b, c, d
    float det  = cv.x * cv.w - cv.y * cv.z;
    float rdet = RCPF(det);
    float vm0  = m.x;
    float vm1  = m.y;
    float vi00 =  cv.w * rdet * K2;
    float vi01 = -cv.y * rdet * K2;
    float vi11 =  cv.x * rdet * K2;
    float vlc  = LOG2F_(w) - LOG2_2PI - 0.5f * LOG2F_(det);

    // ---- this thread's 2 z values ----
    const float2* z2 = (const float2*)z;      // [B*K]
    float2 za = z2[(size_t)(b0 + lane)      * K_KP + k];
    float2 zb = z2[(size_t)(b0 + lane + 64) * K_KP + k];
    v2f ZX = {za.x, zb.x};
    v2f ZY = {za.y, zb.y};
    v2f pdf = {0.f, 0.f}, G0 = {0.f, 0.f}, G1 = {0.f, 0.f};

    // ---- main loop: broadcast component c's constants, evaluate ----
#pragma unroll
    for (int c = 0; c < C_COMP; ++c) {
        float m0  = rlane(vm0, c);
        float m1  = rlane(vm1, c);
        float i00 = rlane(vi00, c);
        float i01 = rlane(vi01, c);
        float i11 = rlane(vi11, c);
        float lc  = rlane(vlc, c);
        EVAL(m0, m1, i00, i01, i11, lc);
    }

    // ---- epilogue ----
    float2 sc = ((const float2*)scale)[k];        // wave-uniform
    const float NEG_INV_K2 = -1.3862943611f;      // -1/K2 = -2 ln 2
    float f0 = sc.x * NEG_INV_K2;                 // fold unnorm scale + sign + 1/k2
    float f1 = sc.y * NEG_INV_K2;
    const int KK2 = 2 * K_KP;                     // 256
    float* out0 = out;
    float* out1 = out + (size_t)B * KK2;

    float pdfj[2] = {pdf.x, pdf.y};
    float gs0j[2] = {G0.x, G0.y};
    float gs1j[2] = {G1.x, G1.y};
#pragma unroll
    for (int j = 0; j < 2; ++j) {
        int b = b0 + lane + j * 64;
        // density_norm = sigmoid((pdf + eps)/tau) = sigmoid(2*pdf - 1)
        float x  = 2.0f * pdfj[j] - 1.0f;
        float ex = EXP2F(-1.44269504f * x);
        float dn = RCPF(1.0f + ex);
        // gradient branch
        float g0 = gs0j[j] * f0;                  // grad_raw
        float g1 = gs1j[j] * f1;
        float n2 = fmaf(g0, g0, g1 * g1);
        float rn = RSQF(n2);
        float nrm = n2 * rn;                      // |grad_raw|
        // mag = exp((5500 - nrm)/1100) = exp2(7.2134752 - nrm*log2(e)/1100)
        float mag = EXP2F(fmaf(nrm, -0.0013115409f, 7.2134752044f));
        float mm = rn * mag;
        ((float2*)(out0 + (size_t)b * KK2 + 2 * k))[0] = make_float2(dn, dn);
        ((float2*)(out1 + (size_t)b * KK2 + 2 * k))[0] = make_float2(g0 * mm, g1 * mm);
    }
}

extern "C" void kernel_launch(void* const* d_in, const int* in_sizes, int n_in,
                              void* d_out, int out_size, void* d_ws, size_t ws_size,
                              hipStream_t stream) {
    const float* z       = (const float*)d_in[0];
    const float* weights = (const float*)d_in[1];
    const float* means   = (const float*)d_in[2];
    const float* covs    = (const float*)d_in[3];
    const float* scale   = (const float*)d_in[4];
    float* out = (float*)d_out;

    int B = in_sizes[0] / (2 * K_KP);            // 4096
    int grid = (K_KP / KPB) * (B / 128);         // 32 * 32 = 1024
    recovery_kernel<<<grid, 256, 0, stream>>>(z, weights, means, covs, scale, out, B);
}